// Round 4
// baseline (686.014 us; speedup 1.0000x reference)
//
#include <hip/hip_runtime.h>
#include <hip/hip_bf16.h>

#define N_NODES  100000
#define N_EDGES  1600000
#define D_FEAT   128
#define HIDDEN   128
#define N_CLASSES 10
#define NUM_GRAPHS 64

typedef __bf16 bf16x8 __attribute__((ext_vector_type(8)));
typedef float  f32x4  __attribute__((ext_vector_type(4)));

static __device__ __forceinline__ float bf2f(unsigned short u) {
    unsigned int x = ((unsigned int)u) << 16;
    return __builtin_bit_cast(float, x);
}
static __device__ __forceinline__ unsigned short f2bf(float f) {
    __bf16 b = (__bf16)f;
    return __builtin_bit_cast(unsigned short, b);
}

// ---------------------------------------------------------------------------
// Convert all 6 fp32 weight matrices to bf16 in one launch.
// ---------------------------------------------------------------------------
__global__ void conv_w6_kernel(const float* __restrict__ W0, const float* __restrict__ W1,
                               const float* __restrict__ W2, const float* __restrict__ W3,
                               const float* __restrict__ W4, const float* __restrict__ W5,
                               __bf16* __restrict__ out) {
    const float* Ws[6] = {W0, W1, W2, W3, W4, W5};
    int m = blockIdx.x >> 6;
    int i = (blockIdx.x & 63) * 256 + threadIdx.x;
    out[m * (HIDDEN * D_FEAT) + i] = (__bf16)Ws[m][i];
}

// ---------------------------------------------------------------------------
// CSR build: histogram, block scan x3, XCD-grouped fill
// ---------------------------------------------------------------------------
__global__ __launch_bounds__(256) void hist_kernel(const int* __restrict__ ei, int* __restrict__ cnt) {
    int e = blockIdx.x * 256 + threadIdx.x;
    if (e < N_EDGES) atomicAdd(&cnt[ei[N_EDGES + e]], 1);
}

__global__ __launch_bounds__(256) void scan1_kernel(const int* __restrict__ cnt,
                                                    int* __restrict__ rp,
                                                    int* __restrict__ bsum, int N) {
    __shared__ int tmp[256];
    int t = threadIdx.x;
    int base = blockIdx.x * 1024 + t * 4;
    int v[4];
    #pragma unroll
    for (int i = 0; i < 4; i++) v[i] = (base + i < N) ? cnt[base + i] : 0;
    int s = v[0] + v[1] + v[2] + v[3];
    tmp[t] = s;
    __syncthreads();
    for (int off = 1; off < 256; off <<= 1) {
        int x = (t >= off) ? tmp[t - off] : 0;
        __syncthreads();
        tmp[t] += x;
        __syncthreads();
    }
    int excl = tmp[t] - s;
    if (t == 255) bsum[blockIdx.x] = tmp[255];
    int run = excl;
    #pragma unroll
    for (int i = 0; i < 4; i++) {
        if (base + i < N) rp[base + i] = run;
        run += v[i];
    }
}

__global__ __launch_bounds__(128) void scan2_kernel(int* __restrict__ bsum, int nb) {
    __shared__ int tmp[128];
    int t = threadIdx.x;
    int v = (t < nb) ? bsum[t] : 0;
    tmp[t] = v;
    __syncthreads();
    for (int off = 1; off < 128; off <<= 1) {
        int x = (t >= off) ? tmp[t - off] : 0;
        __syncthreads();
        tmp[t] += x;
        __syncthreads();
    }
    if (t < nb) bsum[t] = tmp[t] - v;
}

__global__ __launch_bounds__(256) void scan3_kernel(int* __restrict__ rp,
                                                    const int* __restrict__ bsum,
                                                    int* __restrict__ cursor, int N) {
    int i = blockIdx.x * 256 + threadIdx.x;
    if (i < N) {
        int v = rp[i] + bsum[i >> 10];
        rp[i] = v;
        cursor[i] = v;
    }
    if (i == N) rp[N] = N_EDGES;
}

// XCD-grouped fill: group g = blockIdx&7 owns dst ranges r (=d/6250, 0..15)
// with (r&7)==g. csr region per group ~0.8MB -> fits XCD L2, writes merge.
__global__ __launch_bounds__(256) void fill_kernel(
    const int* __restrict__ ei, int* __restrict__ cursor, int* __restrict__ csr_src)
{
    const int NSWEEP = 128;
    int g = blockIdx.x & 7;
    int sweep = blockIdx.x >> 3;
    for (int e = sweep * 256 + threadIdx.x; e < N_EDGES; e += NSWEEP * 256) {
        int d = ei[N_EDGES + e];
        int r = d / 6250;
        if ((r & 7) == g) {
            int pos = atomicAdd(&cursor[d], 1);
            csr_src[pos] = ei[e];
        }
    }
}

// ---------------------------------------------------------------------------
// Dual GEMM (operand-swapped): out_l = h@Wl.T (bf16), out_r = h@Wr.T + b (fp32)
// MFMA A-operand := W rows, B-operand := h rows  =>  D: col=node, row=feature.
// Each lane ends with 4 CONSECUTIVE features of one node -> vector stores.
// ---------------------------------------------------------------------------
template<bool ABF16>
__global__ __launch_bounds__(256) void dual_gemm_kernel(
    const void* __restrict__ hv,
    const __bf16* __restrict__ Wl, const __bf16* __restrict__ Wr,
    const float* __restrict__ bias,
    __bf16* __restrict__ out_l, float* __restrict__ out_r, int M)
{
    const int wave = threadIdx.x >> 6;
    const int lane = threadIdx.x & 63;
    const int m_base = blockIdx.x * 64 + wave * 16;
    const int kq = lane >> 4;
    const int ln = lane & 15;

    int row = m_base + ln;
    int rowc = row < M ? row : (M - 1);

    // h fragments (B-operand): lane holds h[node=ln][k=kc*32+kq*8 .. +7]
    bf16x8 hfrag[4];
    if constexpr (ABF16) {
        const __bf16* hrow = ((const __bf16*)hv) + (size_t)rowc * 128;
        #pragma unroll
        for (int kc = 0; kc < 4; kc++)
            hfrag[kc] = *(const bf16x8*)(hrow + kc * 32 + kq * 8);
    } else {
        const float* hrow = ((const float*)hv) + (size_t)rowc * 128;
        #pragma unroll
        for (int kc = 0; kc < 4; kc++) {
            int k0 = kc * 32 + kq * 8;
            float4 v0 = *(const float4*)(hrow + k0);
            float4 v1 = *(const float4*)(hrow + k0 + 4);
            bf16x8 a;
            a[0] = (__bf16)v0.x; a[1] = (__bf16)v0.y; a[2] = (__bf16)v0.z; a[3] = (__bf16)v0.w;
            a[4] = (__bf16)v1.x; a[5] = (__bf16)v1.y; a[6] = (__bf16)v1.z; a[7] = (__bf16)v1.w;
            hfrag[kc] = a;
        }
    }

    f32x4 accl[8], accr[8];
    #pragma unroll
    for (int nt = 0; nt < 8; nt++) { accl[nt] = (f32x4)(0.f); accr[nt] = (f32x4)(0.f); }

    #pragma unroll
    for (int kc = 0; kc < 4; kc++) {
        int k0 = kc * 32 + kq * 8;
        #pragma unroll
        for (int nt = 0; nt < 8; nt++) {
            // W fragment (A-operand): lane holds W[nt*16+ln][k0..k0+7]
            bf16x8 wl = *(const bf16x8*)(Wl + (nt * 16 + ln) * 128 + k0);
            bf16x8 wr = *(const bf16x8*)(Wr + (nt * 16 + ln) * 128 + k0);
            accl[nt] = __builtin_amdgcn_mfma_f32_16x16x32_bf16(wl, hfrag[kc], accl[nt], 0, 0, 0);
            accr[nt] = __builtin_amdgcn_mfma_f32_16x16x32_bf16(wr, hfrag[kc], accr[nt], 0, 0, 0);
        }
    }

    // D: lane holds node = m_base+ln, feats nt*16 + kq*4 + (0..3)
    int node = m_base + ln;
    if (node < M) {
        size_t rowoff = (size_t)node * 128;
        #pragma unroll
        for (int nt = 0; nt < 8; nt++) {
            int fc = nt * 16 + kq * 4;
            float4 b4 = *(const float4*)(bias + fc);
            ushort4 o;
            o.x = f2bf(accl[nt][0]); o.y = f2bf(accl[nt][1]);
            o.z = f2bf(accl[nt][2]); o.w = f2bf(accl[nt][3]);
            *(ushort4*)(out_l + rowoff + fc) = o;
            float4 vr;
            vr.x = accr[nt][0] + b4.x; vr.y = accr[nt][1] + b4.y;
            vr.z = accr[nt][2] + b4.z; vr.w = accr[nt][3] + b4.w;
            *(float4*)(out_r + rowoff + fc) = vr;
        }
    }
}

// ---------------------------------------------------------------------------
// CSR gather-aggregate: out[n] = base[n] + sum_j hl[csr_src[j]]
// 16 lanes per node (bf16x8 = 16B per lane), 4 nodes per wave.
// ---------------------------------------------------------------------------
template<bool RELU, bool OUTBF16>
__global__ __launch_bounds__(256) void gather_kernel(
    const __bf16* __restrict__ hl, const int* __restrict__ rp,
    const int* __restrict__ csr_src, const float* __restrict__ base,
    void* __restrict__ outp, int N)
{
    int nid = blockIdx.x * 16 + (threadIdx.x >> 4);
    if (nid >= N) return;
    int f8 = threadIdx.x & 15;           // 8 feats per lane
    int start = rp[nid], end = rp[nid + 1];

    float4 a0 = ((const float4*)base)[(size_t)nid * 32 + f8 * 2];
    float4 a1 = ((const float4*)base)[(size_t)nid * 32 + f8 * 2 + 1];

    int j = start;
    for (; j + 1 < end; j += 2) {
        int s0 = csr_src[j];
        int s1 = csr_src[j + 1];
        bf16x8 u0 = ((const bf16x8*)hl)[(size_t)s0 * 16 + f8];
        bf16x8 u1 = ((const bf16x8*)hl)[(size_t)s1 * 16 + f8];
        a0.x += (float)u0[0] + (float)u1[0];
        a0.y += (float)u0[1] + (float)u1[1];
        a0.z += (float)u0[2] + (float)u1[2];
        a0.w += (float)u0[3] + (float)u1[3];
        a1.x += (float)u0[4] + (float)u1[4];
        a1.y += (float)u0[5] + (float)u1[5];
        a1.z += (float)u0[6] + (float)u1[6];
        a1.w += (float)u0[7] + (float)u1[7];
    }
    if (j < end) {
        int s0 = csr_src[j];
        bf16x8 u0 = ((const bf16x8*)hl)[(size_t)s0 * 16 + f8];
        a0.x += (float)u0[0]; a0.y += (float)u0[1];
        a0.z += (float)u0[2]; a0.w += (float)u0[3];
        a1.x += (float)u0[4]; a1.y += (float)u0[5];
        a1.z += (float)u0[6]; a1.w += (float)u0[7];
    }
    if (RELU) {
        a0.x = fmaxf(a0.x, 0.f); a0.y = fmaxf(a0.y, 0.f);
        a0.z = fmaxf(a0.z, 0.f); a0.w = fmaxf(a0.w, 0.f);
        a1.x = fmaxf(a1.x, 0.f); a1.y = fmaxf(a1.y, 0.f);
        a1.z = fmaxf(a1.z, 0.f); a1.w = fmaxf(a1.w, 0.f);
    }
    if (OUTBF16) {
        bf16x8 o;
        o[0] = (__bf16)a0.x; o[1] = (__bf16)a0.y; o[2] = (__bf16)a0.z; o[3] = (__bf16)a0.w;
        o[4] = (__bf16)a1.x; o[5] = (__bf16)a1.y; o[6] = (__bf16)a1.z; o[7] = (__bf16)a1.w;
        ((bf16x8*)outp)[(size_t)nid * 16 + f8] = o;
    } else {
        ((float4*)outp)[(size_t)nid * 32 + f8 * 2] = a0;
        ((float4*)outp)[(size_t)nid * 32 + f8 * 2 + 1] = a1;
    }
}

// ---------------------------------------------------------------------------
// Pool: pooled[batch[n]] += h[n]. batch sorted; 32-node chunks per thread.
// ---------------------------------------------------------------------------
__global__ __launch_bounds__(256) void pool_kernel(
    const float* __restrict__ h, const int* __restrict__ batch,
    float* __restrict__ pooled, int N)
{
    int idx = blockIdx.x * 256 + threadIdx.x;
    int f = idx & 127;
    int chunk = idx >> 7;
    int n0 = chunk * 32;
    if (n0 >= N) return;
    int n1 = n0 + 32; if (n1 > N) n1 = N;
    int curb = batch[n0];
    float acc = 0.f;
    for (int n = n0; n < n1; n++) {
        int b = batch[n];
        if (b != curb) {
            unsafeAtomicAdd(&pooled[(size_t)curb * 128 + f], acc);
            acc = 0.f; curb = b;
        }
        acc += h[(size_t)n * 128 + f];
    }
    unsafeAtomicAdd(&pooled[(size_t)curb * 128 + f], acc);
}

__global__ void final_gemm_kernel(
    const float* __restrict__ pooled, const float* __restrict__ Wout,
    const float* __restrict__ bout, float* __restrict__ out)
{
    int idx = blockIdx.x * 64 + threadIdx.x;
    if (idx < NUM_GRAPHS * N_CLASSES) {
        int g = idx / N_CLASSES;
        int c = idx % N_CLASSES;
        float acc = bout[c];
        for (int k = 0; k < HIDDEN; k++)
            acc += pooled[g * HIDDEN + k] * Wout[c * HIDDEN + k];
        out[idx] = acc;
    }
}

extern "C" void kernel_launch(void* const* d_in, const int* in_sizes, int n_in,
                              void* d_out, int out_size, void* d_ws, size_t ws_size,
                              hipStream_t stream) {
    const float* x     = (const float*)d_in[0];
    const int*   ei    = (const int*)d_in[1];
    const int*   batch = (const int*)d_in[2];
    const float* W1l = (const float*)d_in[3];
    const float* b1  = (const float*)d_in[4];
    const float* W1r = (const float*)d_in[5];
    const float* W2l = (const float*)d_in[6];
    const float* b2  = (const float*)d_in[7];
    const float* W2r = (const float*)d_in[8];
    const float* W3l = (const float*)d_in[9];
    const float* b3  = (const float*)d_in[10];
    const float* W3r = (const float*)d_in[11];
    const float* Wout = (const float*)d_in[12];
    const float* bout = (const float*)d_in[13];
    float* out = (float*)d_out;

    char* ws = (char*)d_ws;
    size_t off = 0;
    __bf16* bufL  = (__bf16*)(ws + off); off += (size_t)N_NODES * 128 * sizeof(__bf16);
    float*  bufR  = (float*)(ws + off);  off += (size_t)N_NODES * 128 * sizeof(float);
    __bf16* bufH  = (__bf16*)(ws + off); off += (size_t)N_NODES * 128 * sizeof(__bf16);
    float* pooled = (float*)(ws + off);  off += (size_t)NUM_GRAPHS * HIDDEN * sizeof(float);
    __bf16* wbf   = (__bf16*)(ws + off); off += 6 * (size_t)HIDDEN * D_FEAT * sizeof(__bf16);
    int* cnt      = (int*)(ws + off);    off += (size_t)N_NODES * sizeof(int);
    int* rp       = (int*)(ws + off);    off += ((size_t)N_NODES + 16) * sizeof(int);
    int* cursor   = (int*)(ws + off);    off += (size_t)N_NODES * sizeof(int);
    int* bsum     = (int*)(ws + off);    off += 128 * sizeof(int);
    int* csr_src  = (int*)(ws + off);    off += (size_t)N_EDGES * sizeof(int);

    const int WSZ = HIDDEN * D_FEAT;

    conv_w6_kernel<<<6 * 64, 256, 0, stream>>>(W1l, W1r, W2l, W2r, W3l, W3r, wbf);

    // CSR build
    hipMemsetAsync(cnt, 0, (size_t)N_NODES * sizeof(int), stream);
    const int egrid = (N_EDGES + 255) / 256;
    hist_kernel<<<egrid, 256, 0, stream>>>(ei, cnt);
    const int nscan = (N_NODES + 1023) / 1024;
    scan1_kernel<<<nscan, 256, 0, stream>>>(cnt, rp, bsum, N_NODES);
    scan2_kernel<<<1, 128, 0, stream>>>(bsum, nscan);
    scan3_kernel<<<(N_NODES + 256) / 256, 256, 0, stream>>>(rp, bsum, cursor, N_NODES);
    fill_kernel<<<8 * 128, 256, 0, stream>>>(ei, cursor, csr_src);

    const int gemm_grid = (N_NODES + 63) / 64;
    const int gath_grid = (N_NODES + 15) / 16;

    // Layer 1
    dual_gemm_kernel<false><<<gemm_grid, 256, 0, stream>>>(x, wbf + 0 * WSZ, wbf + 1 * WSZ, b1, bufL, bufR, N_NODES);
    gather_kernel<true, true><<<gath_grid, 256, 0, stream>>>(bufL, rp, csr_src, bufR, bufH, N_NODES);

    // Layer 2
    dual_gemm_kernel<true><<<gemm_grid, 256, 0, stream>>>(bufH, wbf + 2 * WSZ, wbf + 3 * WSZ, b2, bufL, bufR, N_NODES);
    gather_kernel<true, true><<<gath_grid, 256, 0, stream>>>(bufL, rp, csr_src, bufR, bufH, N_NODES);

    // Layer 3 (gather fp32 in-place into bufR, no relu)
    dual_gemm_kernel<true><<<gemm_grid, 256, 0, stream>>>(bufH, wbf + 4 * WSZ, wbf + 5 * WSZ, b3, bufL, bufR, N_NODES);
    gather_kernel<false, false><<<gath_grid, 256, 0, stream>>>(bufL, rp, csr_src, bufR, bufR, N_NODES);

    // Pool + final
    hipMemsetAsync(pooled, 0, (size_t)NUM_GRAPHS * HIDDEN * sizeof(float), stream);
    const int pool_grid = ((N_NODES + 31) / 32 * 128 + 255) / 256;
    pool_kernel<<<pool_grid, 256, 0, stream>>>(bufR, batch, pooled, N_NODES);
    final_gemm_kernel<<<10, 64, 0, stream>>>(pooled, Wout, bout, out);
}

// Round 5
// 590.898 us; speedup vs baseline: 1.1610x; 1.1610x over previous
//
#include <hip/hip_runtime.h>
#include <hip/hip_bf16.h>

#define N_NODES  100000
#define N_EDGES  1600000
#define D_FEAT   128
#define HIDDEN   128
#define N_CLASSES 10
#define NUM_GRAPHS 64

typedef __bf16 bf16x8 __attribute__((ext_vector_type(8)));
typedef float  f32x4  __attribute__((ext_vector_type(4)));

static __device__ __forceinline__ unsigned short f2bf(float f) {
    __bf16 b = (__bf16)f;
    return __builtin_bit_cast(unsigned short, b);
}

// ---------------------------------------------------------------------------
// Convert all 6 fp32 weight matrices to bf16 in one launch.
// ---------------------------------------------------------------------------
__global__ void conv_w6_kernel(const float* __restrict__ W0, const float* __restrict__ W1,
                               const float* __restrict__ W2, const float* __restrict__ W3,
                               const float* __restrict__ W4, const float* __restrict__ W5,
                               __bf16* __restrict__ out) {
    const float* Ws[6] = {W0, W1, W2, W3, W4, W5};
    int m = blockIdx.x >> 6;
    int i = (blockIdx.x & 63) * 256 + threadIdx.x;
    out[m * (HIDDEN * D_FEAT) + i] = (__bf16)Ws[m][i];
}

// ---------------------------------------------------------------------------
// CSR build: histogram, scan x3, XCD-grouped fill. ei reads are non-temporal
// so streaming doesn't evict the hot cnt/cursor/csr lines from L2.
// ---------------------------------------------------------------------------
__global__ __launch_bounds__(256) void hist_kernel(const int* __restrict__ ei, int* __restrict__ cnt) {
    int e = blockIdx.x * 256 + threadIdx.x;
    if (e < N_EDGES) {
        int d = __builtin_nontemporal_load(ei + N_EDGES + e);
        atomicAdd(&cnt[d], 1);
    }
}

__global__ __launch_bounds__(256) void scan1_kernel(const int* __restrict__ cnt,
                                                    int* __restrict__ rp,
                                                    int* __restrict__ bsum, int N) {
    __shared__ int tmp[256];
    int t = threadIdx.x;
    int base = blockIdx.x * 1024 + t * 4;
    int v[4];
    #pragma unroll
    for (int i = 0; i < 4; i++) v[i] = (base + i < N) ? cnt[base + i] : 0;
    int s = v[0] + v[1] + v[2] + v[3];
    tmp[t] = s;
    __syncthreads();
    for (int off = 1; off < 256; off <<= 1) {
        int x = (t >= off) ? tmp[t - off] : 0;
        __syncthreads();
        tmp[t] += x;
        __syncthreads();
    }
    int excl = tmp[t] - s;
    if (t == 255) bsum[blockIdx.x] = tmp[255];
    int run = excl;
    #pragma unroll
    for (int i = 0; i < 4; i++) {
        if (base + i < N) rp[base + i] = run;
        run += v[i];
    }
}

__global__ __launch_bounds__(128) void scan2_kernel(int* __restrict__ bsum, int nb) {
    __shared__ int tmp[128];
    int t = threadIdx.x;
    int v = (t < nb) ? bsum[t] : 0;
    tmp[t] = v;
    __syncthreads();
    for (int off = 1; off < 128; off <<= 1) {
        int x = (t >= off) ? tmp[t - off] : 0;
        __syncthreads();
        tmp[t] += x;
        __syncthreads();
    }
    if (t < nb) bsum[t] = tmp[t] - v;
}

__global__ __launch_bounds__(256) void scan3_kernel(int* __restrict__ rp,
                                                    const int* __restrict__ bsum,
                                                    int* __restrict__ cursor, int N) {
    int i = blockIdx.x * 256 + threadIdx.x;
    if (i < N) {
        int v = rp[i] + bsum[i >> 10];
        rp[i] = v;
        cursor[i] = v;
    }
    if (i == N) rp[N] = N_EDGES;
}

__global__ __launch_bounds__(256) void fill_kernel(
    const int* __restrict__ ei, int* __restrict__ cursor, int* __restrict__ csr_src)
{
    const int NSWEEP = 128;
    int g = blockIdx.x & 7;
    int sweep = blockIdx.x >> 3;
    for (int e = sweep * 256 + threadIdx.x; e < N_EDGES; e += NSWEEP * 256) {
        int d = __builtin_nontemporal_load(ei + N_EDGES + e);
        int r = d / 6250;
        if ((r & 7) == g) {
            int s = __builtin_nontemporal_load(ei + e);
            int pos = atomicAdd(&cursor[d], 1);
            csr_src[pos] = s;
        }
    }
}

// ---------------------------------------------------------------------------
// Dual GEMM, register-resident W:
//   out_l = h@Wl.T (bf16), out_r = h@Wr.T + b (bf16)
// Block = 64 nodes, wave w owns feats [32w,32w+32). W fragments (16 loads,
// both mats) stay in VGPRs across 4 node-tiles => ~1 mem instr per node.
// MFMA: A=W rows, B=h rows => D: col=node, row=feat (4 consecutive per lane).
// ---------------------------------------------------------------------------
template<bool ABF16>
__global__ __launch_bounds__(256) void dual_gemm_kernel(
    const void* __restrict__ hv,
    const __bf16* __restrict__ Wl, const __bf16* __restrict__ Wr,
    const float* __restrict__ bias,
    __bf16* __restrict__ out_l, __bf16* __restrict__ out_r, int M)
{
    const int wave = threadIdx.x >> 6;
    const int lane = threadIdx.x & 63;
    const int kq = lane >> 4;
    const int ln = lane & 15;
    const int node_base = blockIdx.x * 64;
    const int f_base = wave * 32;

    // W fragments: [mat][t][kc], resident for whole block
    bf16x8 wfrag[2][2][4];
    #pragma unroll
    for (int t = 0; t < 2; t++) {
        int wrow = f_base + t * 16 + ln;
        #pragma unroll
        for (int kc = 0; kc < 4; kc++) {
            int k0 = kc * 32 + kq * 8;
            wfrag[0][t][kc] = *(const bf16x8*)(Wl + wrow * 128 + k0);
            wfrag[1][t][kc] = *(const bf16x8*)(Wr + wrow * 128 + k0);
        }
    }
    float4 bias4[2];
    bias4[0] = *(const float4*)(bias + f_base + kq * 4);
    bias4[1] = *(const float4*)(bias + f_base + 16 + kq * 4);

    #pragma unroll
    for (int tau = 0; tau < 4; tau++) {
        int node = node_base + tau * 16 + ln;
        int nodec = node < M ? node : (M - 1);

        bf16x8 hfrag[4];
        if constexpr (ABF16) {
            const __bf16* hrow = ((const __bf16*)hv) + (size_t)nodec * 128;
            #pragma unroll
            for (int kc = 0; kc < 4; kc++)
                hfrag[kc] = *(const bf16x8*)(hrow + kc * 32 + kq * 8);
        } else {
            const float* hrow = ((const float*)hv) + (size_t)nodec * 128;
            #pragma unroll
            for (int kc = 0; kc < 4; kc++) {
                int k0 = kc * 32 + kq * 8;
                float4 v0 = *(const float4*)(hrow + k0);
                float4 v1 = *(const float4*)(hrow + k0 + 4);
                bf16x8 a;
                a[0] = (__bf16)v0.x; a[1] = (__bf16)v0.y; a[2] = (__bf16)v0.z; a[3] = (__bf16)v0.w;
                a[4] = (__bf16)v1.x; a[5] = (__bf16)v1.y; a[6] = (__bf16)v1.z; a[7] = (__bf16)v1.w;
                hfrag[kc] = a;
            }
        }

        f32x4 accl[2] = {(f32x4)(0.f), (f32x4)(0.f)};
        f32x4 accr[2] = {(f32x4)(0.f), (f32x4)(0.f)};
        #pragma unroll
        for (int kc = 0; kc < 4; kc++) {
            #pragma unroll
            for (int t = 0; t < 2; t++) {
                accl[t] = __builtin_amdgcn_mfma_f32_16x16x32_bf16(wfrag[0][t][kc], hfrag[kc], accl[t], 0, 0, 0);
                accr[t] = __builtin_amdgcn_mfma_f32_16x16x32_bf16(wfrag[1][t][kc], hfrag[kc], accr[t], 0, 0, 0);
            }
        }

        if (node < M) {
            size_t rowoff = (size_t)node * 128;
            #pragma unroll
            for (int t = 0; t < 2; t++) {
                int fc = f_base + t * 16 + kq * 4;
                ushort4 ol;
                ol.x = f2bf(accl[t][0]); ol.y = f2bf(accl[t][1]);
                ol.z = f2bf(accl[t][2]); ol.w = f2bf(accl[t][3]);
                *(ushort4*)(out_l + rowoff + fc) = ol;
                ushort4 orr;
                orr.x = f2bf(accr[t][0] + bias4[t].x);
                orr.y = f2bf(accr[t][1] + bias4[t].y);
                orr.z = f2bf(accr[t][2] + bias4[t].z);
                orr.w = f2bf(accr[t][3] + bias4[t].w);
                *(ushort4*)(out_r + rowoff + fc) = orr;
            }
        }
    }
}

// ---------------------------------------------------------------------------
// CSR gather-aggregate: out[n] = (relu?)(base[n] + sum_j hl[csr_src[j]])
// All bf16 I/O, fp32 accumulate. 16 lanes per node (bf16x8 per lane).
// ---------------------------------------------------------------------------
template<bool RELU>
__global__ __launch_bounds__(256) void gather_kernel(
    const __bf16* __restrict__ hl, const int* __restrict__ rp,
    const int* __restrict__ csr_src, const __bf16* __restrict__ base,
    __bf16* __restrict__ outp, int N)
{
    int nid = blockIdx.x * 16 + (threadIdx.x >> 4);
    if (nid >= N) return;
    int f8 = threadIdx.x & 15;
    int start = rp[nid], end = rp[nid + 1];

    bf16x8 b8 = ((const bf16x8*)base)[(size_t)nid * 16 + f8];
    float a[8];
    #pragma unroll
    for (int i = 0; i < 8; i++) a[i] = (float)b8[i];

    int j = start;
    for (; j + 1 < end; j += 2) {
        int s0 = csr_src[j];
        int s1 = csr_src[j + 1];
        bf16x8 u0 = ((const bf16x8*)hl)[(size_t)s0 * 16 + f8];
        bf16x8 u1 = ((const bf16x8*)hl)[(size_t)s1 * 16 + f8];
        #pragma unroll
        for (int i = 0; i < 8; i++) a[i] += (float)u0[i] + (float)u1[i];
    }
    if (j < end) {
        int s0 = csr_src[j];
        bf16x8 u0 = ((const bf16x8*)hl)[(size_t)s0 * 16 + f8];
        #pragma unroll
        for (int i = 0; i < 8; i++) a[i] += (float)u0[i];
    }
    bf16x8 o;
    #pragma unroll
    for (int i = 0; i < 8; i++) {
        float v = RELU ? fmaxf(a[i], 0.f) : a[i];
        o[i] = (__bf16)v;
    }
    ((bf16x8*)outp)[(size_t)nid * 16 + f8] = o;
}

// ---------------------------------------------------------------------------
// Pool: pooled[batch[n]] += h[n] (bf16 in, fp32 acc/out). batch sorted.
// ---------------------------------------------------------------------------
__global__ __launch_bounds__(256) void pool_kernel(
    const __bf16* __restrict__ h, const int* __restrict__ batch,
    float* __restrict__ pooled, int N)
{
    int idx = blockIdx.x * 256 + threadIdx.x;
    int f = idx & 127;
    int chunk = idx >> 7;
    int n0 = chunk * 32;
    if (n0 >= N) return;
    int n1 = n0 + 32; if (n1 > N) n1 = N;
    int curb = batch[n0];
    float acc = 0.f;
    for (int n = n0; n < n1; n++) {
        int b = batch[n];
        if (b != curb) {
            unsafeAtomicAdd(&pooled[(size_t)curb * 128 + f], acc);
            acc = 0.f; curb = b;
        }
        acc += (float)h[(size_t)n * 128 + f];
    }
    unsafeAtomicAdd(&pooled[(size_t)curb * 128 + f], acc);
}

__global__ void final_gemm_kernel(
    const float* __restrict__ pooled, const float* __restrict__ Wout,
    const float* __restrict__ bout, float* __restrict__ out)
{
    int idx = blockIdx.x * 64 + threadIdx.x;
    if (idx < NUM_GRAPHS * N_CLASSES) {
        int g = idx / N_CLASSES;
        int c = idx % N_CLASSES;
        float acc = bout[c];
        for (int k = 0; k < HIDDEN; k++)
            acc += pooled[g * HIDDEN + k] * Wout[c * HIDDEN + k];
        out[idx] = acc;
    }
}

extern "C" void kernel_launch(void* const* d_in, const int* in_sizes, int n_in,
                              void* d_out, int out_size, void* d_ws, size_t ws_size,
                              hipStream_t stream) {
    const float* x     = (const float*)d_in[0];
    const int*   ei    = (const int*)d_in[1];
    const int*   batch = (const int*)d_in[2];
    const float* W1l = (const float*)d_in[3];
    const float* b1  = (const float*)d_in[4];
    const float* W1r = (const float*)d_in[5];
    const float* W2l = (const float*)d_in[6];
    const float* b2  = (const float*)d_in[7];
    const float* W2r = (const float*)d_in[8];
    const float* W3l = (const float*)d_in[9];
    const float* b3  = (const float*)d_in[10];
    const float* W3r = (const float*)d_in[11];
    const float* Wout = (const float*)d_in[12];
    const float* bout = (const float*)d_in[13];
    float* out = (float*)d_out;

    char* ws = (char*)d_ws;
    size_t off = 0;
    __bf16* bufL  = (__bf16*)(ws + off); off += (size_t)N_NODES * 128 * sizeof(__bf16);
    __bf16* bufR  = (__bf16*)(ws + off); off += (size_t)N_NODES * 128 * sizeof(__bf16);
    __bf16* bufH  = (__bf16*)(ws + off); off += (size_t)N_NODES * 128 * sizeof(__bf16);
    float* pooled = (float*)(ws + off);  off += (size_t)NUM_GRAPHS * HIDDEN * sizeof(float);
    __bf16* wbf   = (__bf16*)(ws + off); off += 6 * (size_t)HIDDEN * D_FEAT * sizeof(__bf16);
    int* cnt      = (int*)(ws + off);    off += (size_t)N_NODES * sizeof(int);
    int* rp       = (int*)(ws + off);    off += ((size_t)N_NODES + 16) * sizeof(int);
    int* cursor   = (int*)(ws + off);    off += (size_t)N_NODES * sizeof(int);
    int* bsum     = (int*)(ws + off);    off += 128 * sizeof(int);
    int* csr_src  = (int*)(ws + off);    off += (size_t)N_EDGES * sizeof(int);

    const int WSZ = HIDDEN * D_FEAT;

    conv_w6_kernel<<<6 * 64, 256, 0, stream>>>(W1l, W1r, W2l, W2r, W3l, W3r, wbf);

    // CSR build
    hipMemsetAsync(cnt, 0, (size_t)N_NODES * sizeof(int), stream);
    const int egrid = (N_EDGES + 255) / 256;
    hist_kernel<<<egrid, 256, 0, stream>>>(ei, cnt);
    const int nscan = (N_NODES + 1023) / 1024;
    scan1_kernel<<<nscan, 256, 0, stream>>>(cnt, rp, bsum, N_NODES);
    scan2_kernel<<<1, 128, 0, stream>>>(bsum, nscan);
    scan3_kernel<<<(N_NODES + 256) / 256, 256, 0, stream>>>(rp, bsum, cursor, N_NODES);
    fill_kernel<<<8 * 128, 256, 0, stream>>>(ei, cursor, csr_src);

    const int gemm_grid = (N_NODES + 63) / 64;
    const int gath_grid = (N_NODES + 15) / 16;

    // Layer 1
    dual_gemm_kernel<false><<<gemm_grid, 256, 0, stream>>>(x, wbf + 0 * WSZ, wbf + 1 * WSZ, b1, bufL, bufR, N_NODES);
    gather_kernel<true><<<gath_grid, 256, 0, stream>>>(bufL, rp, csr_src, bufR, bufH, N_NODES);

    // Layer 2
    dual_gemm_kernel<true><<<gemm_grid, 256, 0, stream>>>(bufH, wbf + 2 * WSZ, wbf + 3 * WSZ, b2, bufL, bufR, N_NODES);
    gather_kernel<true><<<gath_grid, 256, 0, stream>>>(bufL, rp, csr_src, bufR, bufH, N_NODES);

    // Layer 3 (no relu)
    dual_gemm_kernel<true><<<gemm_grid, 256, 0, stream>>>(bufH, wbf + 4 * WSZ, wbf + 5 * WSZ, b3, bufL, bufR, N_NODES);
    gather_kernel<false><<<gath_grid, 256, 0, stream>>>(bufL, rp, csr_src, bufR, bufH, N_NODES);

    // Pool + final
    hipMemsetAsync(pooled, 0, (size_t)NUM_GRAPHS * HIDDEN * sizeof(float), stream);
    const int pool_grid = ((N_NODES + 31) / 32 * 128 + 255) / 256;
    pool_kernel<<<pool_grid, 256, 0, stream>>>(bufH, batch, pooled, N_NODES);
    final_gemm_kernel<<<10, 64, 0, stream>>>(pooled, Wout, bout, out);
}

// Round 6
// 507.620 us; speedup vs baseline: 1.3514x; 1.1641x over previous
//
#include <hip/hip_runtime.h>
#include <hip/hip_bf16.h>

#define N_NODES  100000
#define N_EDGES  1600000
#define D_FEAT   128
#define HIDDEN   128
#define N_CLASSES 10
#define NUM_GRAPHS 64

#define NBUCK 250        // dst buckets
#define NPB   400        // nodes per bucket (250*400 = 100000 exactly)
#define CHUNK 12500      // edges per block in passes A/C (128*12500 = 1.6M exactly)

typedef __bf16 bf16x8 __attribute__((ext_vector_type(8)));
typedef float  f32x4  __attribute__((ext_vector_type(4)));

static __device__ __forceinline__ unsigned short f2bf(float f) {
    __bf16 b = (__bf16)f;
    return __builtin_bit_cast(unsigned short, b);
}

// ---------------------------------------------------------------------------
// Convert all 6 fp32 weight matrices to bf16 in one launch.
// ---------------------------------------------------------------------------
__global__ void conv_w6_kernel(const float* __restrict__ W0, const float* __restrict__ W1,
                               const float* __restrict__ W2, const float* __restrict__ W3,
                               const float* __restrict__ W4, const float* __restrict__ W5,
                               __bf16* __restrict__ out) {
    const float* Ws[6] = {W0, W1, W2, W3, W4, W5};
    int m = blockIdx.x >> 6;
    int i = (blockIdx.x & 63) * 256 + threadIdx.x;
    out[m * (HIDDEN * D_FEAT) + i] = (__bf16)Ws[m][i];
}

// ---------------------------------------------------------------------------
// Pass A: bucket histogram via LDS (no per-edge global atomics)
// ---------------------------------------------------------------------------
__global__ __launch_bounds__(256) void bucket_hist_kernel(const int* __restrict__ ei,
                                                          int* __restrict__ bh) {
    __shared__ int h[NBUCK];
    int t = threadIdx.x;
    for (int i = t; i < NBUCK; i += 256) h[i] = 0;
    __syncthreads();
    int e0 = blockIdx.x * CHUNK;
    for (int e = e0 + t; e < e0 + CHUNK; e += 256) {
        int d = ei[N_EDGES + e];
        atomicAdd(&h[d / NPB], 1);
    }
    __syncthreads();
    for (int i = t; i < NBUCK; i += 256) atomicAdd(&bh[i], h[i]);
}

// ---------------------------------------------------------------------------
// Pass B: single-block exclusive scan of bucket counts -> bases + cursors
// ---------------------------------------------------------------------------
__global__ __launch_bounds__(256) void bucket_scan_kernel(const int* __restrict__ bh,
                                                          int* __restrict__ bbase,
                                                          int* __restrict__ bcur) {
    __shared__ int tmp[256];
    int t = threadIdx.x;
    int v = (t < NBUCK) ? bh[t] : 0;
    tmp[t] = v;
    __syncthreads();
    for (int off = 1; off < 256; off <<= 1) {
        int x = (t >= off) ? tmp[t - off] : 0;
        __syncthreads();
        tmp[t] += x;
        __syncthreads();
    }
    if (t < NBUCK) { int e = tmp[t] - v; bbase[t] = e; bcur[t] = e; }
    if (t == NBUCK - 1) bbase[NBUCK] = tmp[t];
}

// ---------------------------------------------------------------------------
// Pass C: partition edges into bucket-major int2{src,dst}. Each block claims
// per-bucket ranges wholesale (250 atomics/block), writes ~400B dense chunks.
// ---------------------------------------------------------------------------
__global__ __launch_bounds__(256) void bucket_scatter_kernel(const int* __restrict__ ei,
                                                             int* __restrict__ bcur,
                                                             int2* __restrict__ bkt) {
    __shared__ int h[NBUCK];
    __shared__ int lbase[NBUCK];
    int t = threadIdx.x;
    for (int i = t; i < NBUCK; i += 256) h[i] = 0;
    __syncthreads();
    int e0 = blockIdx.x * CHUNK;
    for (int e = e0 + t; e < e0 + CHUNK; e += 256) {
        int d = ei[N_EDGES + e];
        atomicAdd(&h[d / NPB], 1);
    }
    __syncthreads();
    for (int i = t; i < NBUCK; i += 256) {
        lbase[i] = atomicAdd(&bcur[i], h[i]);
        h[i] = 0;
    }
    __syncthreads();
    for (int e = e0 + t; e < e0 + CHUNK; e += 256) {
        int s = ei[e];
        int d = ei[N_EDGES + e];
        int bb = d / NPB;
        int pos = lbase[bb] + atomicAdd(&h[bb], 1);
        bkt[pos] = make_int2(s, d);
    }
}

// ---------------------------------------------------------------------------
// Pass D: one block per bucket. LDS per-node count -> LDS scan -> rp (dense)
// -> csr fill via LDS cursors into a ~26KB contiguous window (dense writes).
// ---------------------------------------------------------------------------
__global__ __launch_bounds__(256) void bucket_csr_kernel(const int2* __restrict__ bkt,
                                                         const int* __restrict__ bbase,
                                                         int* __restrict__ rp,
                                                         int* __restrict__ csr_src) {
    const int b = blockIdx.x;
    const int n0 = b * NPB;
    const int ebase = bbase[b], eend = bbase[b + 1];
    __shared__ int cnt[NPB];
    __shared__ int part[128];
    __shared__ int excl[NPB];
    int t = threadIdx.x;
    for (int i = t; i < NPB; i += 256) cnt[i] = 0;
    __syncthreads();
    for (int e = ebase + t; e < eend; e += 256) {
        int2 p = bkt[e];
        atomicAdd(&cnt[p.y - n0], 1);
    }
    __syncthreads();
    int gs = 0;
    if (t < 100) { gs = cnt[4 * t] + cnt[4 * t + 1] + cnt[4 * t + 2] + cnt[4 * t + 3]; part[t] = gs; }
    else if (t < 128) part[t] = 0;
    __syncthreads();
    for (int off = 1; off < 128; off <<= 1) {
        int x = 0;
        if (t < 128 && t >= off) x = part[t - off];
        __syncthreads();
        if (t < 128) part[t] += x;
        __syncthreads();
    }
    if (t < 100) part[t] -= gs;   // exclusive group base
    __syncthreads();
    for (int i = t; i < NPB; i += 256) {
        int g = i >> 2;
        int e0 = part[g];
        for (int j = g * 4; j < i; j++) e0 += cnt[j];
        excl[i] = e0;
    }
    __syncthreads();
    for (int i = t; i < NPB; i += 256) {
        rp[n0 + i] = ebase + excl[i];
        cnt[i] = excl[i];          // reuse as cursor
    }
    if (b == NBUCK - 1 && t == 0) rp[N_NODES] = N_EDGES;
    __syncthreads();
    for (int e = ebase + t; e < eend; e += 256) {
        int2 p = bkt[e];
        int pos = ebase + atomicAdd(&cnt[p.y - n0], 1);
        csr_src[pos] = p.x;
    }
}

// ---------------------------------------------------------------------------
// Dual GEMM, register-resident W:
//   out_l = h@Wl.T (bf16), out_r = h@Wr.T + b (bf16)
// Block = 64 nodes, wave w owns feats [32w,32w+32). W fragments (16 loads,
// both mats) stay in VGPRs across 4 node-tiles.
// MFMA: A=W rows, B=h rows => D: col=node, row=feat (4 consecutive per lane).
// ---------------------------------------------------------------------------
template<bool ABF16>
__global__ __launch_bounds__(256) void dual_gemm_kernel(
    const void* __restrict__ hv,
    const __bf16* __restrict__ Wl, const __bf16* __restrict__ Wr,
    const float* __restrict__ bias,
    __bf16* __restrict__ out_l, __bf16* __restrict__ out_r, int M)
{
    const int wave = threadIdx.x >> 6;
    const int lane = threadIdx.x & 63;
    const int kq = lane >> 4;
    const int ln = lane & 15;
    const int node_base = blockIdx.x * 64;
    const int f_base = wave * 32;

    bf16x8 wfrag[2][2][4];
    #pragma unroll
    for (int t = 0; t < 2; t++) {
        int wrow = f_base + t * 16 + ln;
        #pragma unroll
        for (int kc = 0; kc < 4; kc++) {
            int k0 = kc * 32 + kq * 8;
            wfrag[0][t][kc] = *(const bf16x8*)(Wl + wrow * 128 + k0);
            wfrag[1][t][kc] = *(const bf16x8*)(Wr + wrow * 128 + k0);
        }
    }
    float4 bias4[2];
    bias4[0] = *(const float4*)(bias + f_base + kq * 4);
    bias4[1] = *(const float4*)(bias + f_base + 16 + kq * 4);

    #pragma unroll
    for (int tau = 0; tau < 4; tau++) {
        int node = node_base + tau * 16 + ln;
        int nodec = node < M ? node : (M - 1);

        bf16x8 hfrag[4];
        if constexpr (ABF16) {
            const __bf16* hrow = ((const __bf16*)hv) + (size_t)nodec * 128;
            #pragma unroll
            for (int kc = 0; kc < 4; kc++)
                hfrag[kc] = *(const bf16x8*)(hrow + kc * 32 + kq * 8);
        } else {
            const float* hrow = ((const float*)hv) + (size_t)nodec * 128;
            #pragma unroll
            for (int kc = 0; kc < 4; kc++) {
                int k0 = kc * 32 + kq * 8;
                float4 v0 = *(const float4*)(hrow + k0);
                float4 v1 = *(const float4*)(hrow + k0 + 4);
                bf16x8 a;
                a[0] = (__bf16)v0.x; a[1] = (__bf16)v0.y; a[2] = (__bf16)v0.z; a[3] = (__bf16)v0.w;
                a[4] = (__bf16)v1.x; a[5] = (__bf16)v1.y; a[6] = (__bf16)v1.z; a[7] = (__bf16)v1.w;
                hfrag[kc] = a;
            }
        }

        f32x4 accl[2] = {(f32x4)(0.f), (f32x4)(0.f)};
        f32x4 accr[2] = {(f32x4)(0.f), (f32x4)(0.f)};
        #pragma unroll
        for (int kc = 0; kc < 4; kc++) {
            #pragma unroll
            for (int t = 0; t < 2; t++) {
                accl[t] = __builtin_amdgcn_mfma_f32_16x16x32_bf16(wfrag[0][t][kc], hfrag[kc], accl[t], 0, 0, 0);
                accr[t] = __builtin_amdgcn_mfma_f32_16x16x32_bf16(wfrag[1][t][kc], hfrag[kc], accr[t], 0, 0, 0);
            }
        }

        if (node < M) {
            size_t rowoff = (size_t)node * 128;
            #pragma unroll
            for (int t = 0; t < 2; t++) {
                int fc = f_base + t * 16 + kq * 4;
                ushort4 ol;
                ol.x = f2bf(accl[t][0]); ol.y = f2bf(accl[t][1]);
                ol.z = f2bf(accl[t][2]); ol.w = f2bf(accl[t][3]);
                *(ushort4*)(out_l + rowoff + fc) = ol;
                ushort4 orr;
                orr.x = f2bf(accr[t][0] + bias4[t].x);
                orr.y = f2bf(accr[t][1] + bias4[t].y);
                orr.z = f2bf(accr[t][2] + bias4[t].z);
                orr.w = f2bf(accr[t][3] + bias4[t].w);
                *(ushort4*)(out_r + rowoff + fc) = orr;
            }
        }
    }
}

// ---------------------------------------------------------------------------
// CSR gather-aggregate: out[n] = (relu?)(base[n] + sum_j hl[csr_src[j]])
// All bf16 I/O, fp32 accumulate. 16 lanes per node (bf16x8 per lane).
// ---------------------------------------------------------------------------
template<bool RELU>
__global__ __launch_bounds__(256) void gather_kernel(
    const __bf16* __restrict__ hl, const int* __restrict__ rp,
    const int* __restrict__ csr_src, const __bf16* __restrict__ base,
    __bf16* __restrict__ outp, int N)
{
    int nid = blockIdx.x * 16 + (threadIdx.x >> 4);
    if (nid >= N) return;
    int f8 = threadIdx.x & 15;
    int start = rp[nid], end = rp[nid + 1];

    bf16x8 b8 = ((const bf16x8*)base)[(size_t)nid * 16 + f8];
    float a[8];
    #pragma unroll
    for (int i = 0; i < 8; i++) a[i] = (float)b8[i];

    int j = start;
    for (; j + 1 < end; j += 2) {
        int s0 = csr_src[j];
        int s1 = csr_src[j + 1];
        bf16x8 u0 = ((const bf16x8*)hl)[(size_t)s0 * 16 + f8];
        bf16x8 u1 = ((const bf16x8*)hl)[(size_t)s1 * 16 + f8];
        #pragma unroll
        for (int i = 0; i < 8; i++) a[i] += (float)u0[i] + (float)u1[i];
    }
    if (j < end) {
        int s0 = csr_src[j];
        bf16x8 u0 = ((const bf16x8*)hl)[(size_t)s0 * 16 + f8];
        #pragma unroll
        for (int i = 0; i < 8; i++) a[i] += (float)u0[i];
    }
    bf16x8 o;
    #pragma unroll
    for (int i = 0; i < 8; i++) {
        float v = RELU ? fmaxf(a[i], 0.f) : a[i];
        o[i] = (__bf16)v;
    }
    ((bf16x8*)outp)[(size_t)nid * 16 + f8] = o;
}

// ---------------------------------------------------------------------------
// Pool: pooled[batch[n]] += h[n] (bf16 in, fp32 acc/out). batch sorted.
// ---------------------------------------------------------------------------
__global__ __launch_bounds__(256) void pool_kernel(
    const __bf16* __restrict__ h, const int* __restrict__ batch,
    float* __restrict__ pooled, int N)
{
    int idx = blockIdx.x * 256 + threadIdx.x;
    int f = idx & 127;
    int chunk = idx >> 7;
    int n0 = chunk * 32;
    if (n0 >= N) return;
    int n1 = n0 + 32; if (n1 > N) n1 = N;
    int curb = batch[n0];
    float acc = 0.f;
    for (int n = n0; n < n1; n++) {
        int b = batch[n];
        if (b != curb) {
            unsafeAtomicAdd(&pooled[(size_t)curb * 128 + f], acc);
            acc = 0.f; curb = b;
        }
        acc += (float)h[(size_t)n * 128 + f];
    }
    unsafeAtomicAdd(&pooled[(size_t)curb * 128 + f], acc);
}

__global__ void final_gemm_kernel(
    const float* __restrict__ pooled, const float* __restrict__ Wout,
    const float* __restrict__ bout, float* __restrict__ out)
{
    int idx = blockIdx.x * 64 + threadIdx.x;
    if (idx < NUM_GRAPHS * N_CLASSES) {
        int g = idx / N_CLASSES;
        int c = idx % N_CLASSES;
        float acc = bout[c];
        for (int k = 0; k < HIDDEN; k++)
            acc += pooled[g * HIDDEN + k] * Wout[c * HIDDEN + k];
        out[idx] = acc;
    }
}

extern "C" void kernel_launch(void* const* d_in, const int* in_sizes, int n_in,
                              void* d_out, int out_size, void* d_ws, size_t ws_size,
                              hipStream_t stream) {
    const float* x     = (const float*)d_in[0];
    const int*   ei    = (const int*)d_in[1];
    const int*   batch = (const int*)d_in[2];
    const float* W1l = (const float*)d_in[3];
    const float* b1  = (const float*)d_in[4];
    const float* W1r = (const float*)d_in[5];
    const float* W2l = (const float*)d_in[6];
    const float* b2  = (const float*)d_in[7];
    const float* W2r = (const float*)d_in[8];
    const float* W3l = (const float*)d_in[9];
    const float* b3  = (const float*)d_in[10];
    const float* W3r = (const float*)d_in[11];
    const float* Wout = (const float*)d_in[12];
    const float* bout = (const float*)d_in[13];
    float* out = (float*)d_out;

    char* ws = (char*)d_ws;
    size_t off = 0;
    __bf16* bufL  = (__bf16*)(ws + off); off += (size_t)N_NODES * 128 * sizeof(__bf16);
    __bf16* bufR  = (__bf16*)(ws + off); off += (size_t)N_NODES * 128 * sizeof(__bf16);
    __bf16* bufH  = (__bf16*)(ws + off); off += (size_t)N_NODES * 128 * sizeof(__bf16);
    float* pooled = (float*)(ws + off);  off += (size_t)NUM_GRAPHS * HIDDEN * sizeof(float);
    __bf16* wbf   = (__bf16*)(ws + off); off += 6 * (size_t)HIDDEN * D_FEAT * sizeof(__bf16);
    int* rp       = (int*)(ws + off);    off += ((size_t)N_NODES + 16) * sizeof(int);
    int* csr_src  = (int*)(ws + off);    off += (size_t)N_EDGES * sizeof(int);
    int2* bkt     = (int2*)(ws + off);   off += (size_t)N_EDGES * sizeof(int2);
    int* bh       = (int*)(ws + off);    off += (NBUCK + 8) * sizeof(int);
    int* bbase    = (int*)(ws + off);    off += (NBUCK + 8) * sizeof(int);
    int* bcur     = (int*)(ws + off);    off += (NBUCK + 8) * sizeof(int);

    const int WSZ = HIDDEN * D_FEAT;

    conv_w6_kernel<<<6 * 64, 256, 0, stream>>>(W1l, W1r, W2l, W2r, W3l, W3r, wbf);

    // Bucket-based CSR build (all-dense writes)
    hipMemsetAsync(bh, 0, NBUCK * sizeof(int), stream);
    bucket_hist_kernel<<<128, 256, 0, stream>>>(ei, bh);
    bucket_scan_kernel<<<1, 256, 0, stream>>>(bh, bbase, bcur);
    bucket_scatter_kernel<<<128, 256, 0, stream>>>(ei, bcur, bkt);
    bucket_csr_kernel<<<NBUCK, 256, 0, stream>>>(bkt, bbase, rp, csr_src);

    const int gemm_grid = (N_NODES + 63) / 64;
    const int gath_grid = (N_NODES + 15) / 16;

    // Layer 1
    dual_gemm_kernel<false><<<gemm_grid, 256, 0, stream>>>(x, wbf + 0 * WSZ, wbf + 1 * WSZ, b1, bufL, bufR, N_NODES);
    gather_kernel<true><<<gath_grid, 256, 0, stream>>>(bufL, rp, csr_src, bufR, bufH, N_NODES);

    // Layer 2
    dual_gemm_kernel<true><<<gemm_grid, 256, 0, stream>>>(bufH, wbf + 2 * WSZ, wbf + 3 * WSZ, b2, bufL, bufR, N_NODES);
    gather_kernel<true><<<gath_grid, 256, 0, stream>>>(bufL, rp, csr_src, bufR, bufH, N_NODES);

    // Layer 3 (no relu)
    dual_gemm_kernel<true><<<gemm_grid, 256, 0, stream>>>(bufH, wbf + 4 * WSZ, wbf + 5 * WSZ, b3, bufL, bufR, N_NODES);
    gather_kernel<false><<<gath_grid, 256, 0, stream>>>(bufL, rp, csr_src, bufR, bufH, N_NODES);

    // Pool + final
    hipMemsetAsync(pooled, 0, (size_t)NUM_GRAPHS * HIDDEN * sizeof(float), stream);
    const int pool_grid = ((N_NODES + 31) / 32 * 128 + 255) / 256;
    pool_kernel<<<pool_grid, 256, 0, stream>>>(bufH, batch, pooled, N_NODES);
    final_gemm_kernel<<<10, 64, 0, stream>>>(pooled, Wout, bout, out);
}

// Round 7
// 499.598 us; speedup vs baseline: 1.3731x; 1.0161x over previous
//
#include <hip/hip_runtime.h>
#include <hip/hip_bf16.h>

#define N_NODES  100000
#define N_EDGES  1600000
#define D_FEAT   128
#define HIDDEN   128
#define N_CLASSES 10
#define NUM_GRAPHS 64

#define NBUCK 250        // dst buckets
#define NPB   400        // nodes per bucket (250*400 = 100000 exactly)
#define CHUNK 12500      // edges per block in passes A/C (128*12500 = 1.6M exactly)
#define GEMM_NT 128      // nodes per GEMM block

typedef __bf16 bf16x8 __attribute__((ext_vector_type(8)));
typedef float  f32x4  __attribute__((ext_vector_type(4)));

static __device__ __forceinline__ unsigned short f2bf(float f) {
    __bf16 b = (__bf16)f;
    return __builtin_bit_cast(unsigned short, b);
}

// ---------------------------------------------------------------------------
// Convert all 6 fp32 weight matrices to bf16 in one launch.
// ---------------------------------------------------------------------------
__global__ void conv_w6_kernel(const float* __restrict__ W0, const float* __restrict__ W1,
                               const float* __restrict__ W2, const float* __restrict__ W3,
                               const float* __restrict__ W4, const float* __restrict__ W5,
                               __bf16* __restrict__ out) {
    const float* Ws[6] = {W0, W1, W2, W3, W4, W5};
    int m = blockIdx.x >> 6;
    int i = (blockIdx.x & 63) * 256 + threadIdx.x;
    out[m * (HIDDEN * D_FEAT) + i] = (__bf16)Ws[m][i];
}

// ---------------------------------------------------------------------------
// Pass A: bucket histogram via LDS
// ---------------------------------------------------------------------------
__global__ __launch_bounds__(256) void bucket_hist_kernel(const int* __restrict__ ei,
                                                          int* __restrict__ bh) {
    __shared__ int h[NBUCK];
    int t = threadIdx.x;
    for (int i = t; i < NBUCK; i += 256) h[i] = 0;
    __syncthreads();
    int e0 = blockIdx.x * CHUNK;
    for (int e = e0 + t; e < e0 + CHUNK; e += 256) {
        int d = ei[N_EDGES + e];
        atomicAdd(&h[d / NPB], 1);
    }
    __syncthreads();
    for (int i = t; i < NBUCK; i += 256) atomicAdd(&bh[i], h[i]);
}

// ---------------------------------------------------------------------------
// Pass B: single-block exclusive scan of bucket counts -> bases + cursors
// ---------------------------------------------------------------------------
__global__ __launch_bounds__(256) void bucket_scan_kernel(const int* __restrict__ bh,
                                                          int* __restrict__ bbase,
                                                          int* __restrict__ bcur) {
    __shared__ int tmp[256];
    int t = threadIdx.x;
    int v = (t < NBUCK) ? bh[t] : 0;
    tmp[t] = v;
    __syncthreads();
    for (int off = 1; off < 256; off <<= 1) {
        int x = (t >= off) ? tmp[t - off] : 0;
        __syncthreads();
        tmp[t] += x;
        __syncthreads();
    }
    if (t < NBUCK) { int e = tmp[t] - v; bbase[t] = e; bcur[t] = e; }
    if (t == NBUCK - 1) bbase[NBUCK] = tmp[t];
}

// ---------------------------------------------------------------------------
// Pass C: partition edges into bucket-major int2{src,dst}.
// ---------------------------------------------------------------------------
__global__ __launch_bounds__(256) void bucket_scatter_kernel(const int* __restrict__ ei,
                                                             int* __restrict__ bcur,
                                                             int2* __restrict__ bkt) {
    __shared__ int h[NBUCK];
    __shared__ int lbase[NBUCK];
    int t = threadIdx.x;
    for (int i = t; i < NBUCK; i += 256) h[i] = 0;
    __syncthreads();
    int e0 = blockIdx.x * CHUNK;
    for (int e = e0 + t; e < e0 + CHUNK; e += 256) {
        int d = ei[N_EDGES + e];
        atomicAdd(&h[d / NPB], 1);
    }
    __syncthreads();
    for (int i = t; i < NBUCK; i += 256) {
        lbase[i] = atomicAdd(&bcur[i], h[i]);
        h[i] = 0;
    }
    __syncthreads();
    for (int e = e0 + t; e < e0 + CHUNK; e += 256) {
        int s = ei[e];
        int d = ei[N_EDGES + e];
        int bb = d / NPB;
        int pos = lbase[bb] + atomicAdd(&h[bb], 1);
        bkt[pos] = make_int2(s, d);
    }
}

// ---------------------------------------------------------------------------
// Pass D: one block per bucket -> rp + csr_src (dense writes)
// ---------------------------------------------------------------------------
__global__ __launch_bounds__(256) void bucket_csr_kernel(const int2* __restrict__ bkt,
                                                         const int* __restrict__ bbase,
                                                         int* __restrict__ rp,
                                                         int* __restrict__ csr_src) {
    const int b = blockIdx.x;
    const int n0 = b * NPB;
    const int ebase = bbase[b], eend = bbase[b + 1];
    __shared__ int cnt[NPB];
    __shared__ int part[128];
    __shared__ int excl[NPB];
    int t = threadIdx.x;
    for (int i = t; i < NPB; i += 256) cnt[i] = 0;
    __syncthreads();
    for (int e = ebase + t; e < eend; e += 256) {
        int2 p = bkt[e];
        atomicAdd(&cnt[p.y - n0], 1);
    }
    __syncthreads();
    int gs = 0;
    if (t < 100) { gs = cnt[4 * t] + cnt[4 * t + 1] + cnt[4 * t + 2] + cnt[4 * t + 3]; part[t] = gs; }
    else if (t < 128) part[t] = 0;
    __syncthreads();
    for (int off = 1; off < 128; off <<= 1) {
        int x = 0;
        if (t < 128 && t >= off) x = part[t - off];
        __syncthreads();
        if (t < 128) part[t] += x;
        __syncthreads();
    }
    if (t < 100) part[t] -= gs;
    __syncthreads();
    for (int i = t; i < NPB; i += 256) {
        int g = i >> 2;
        int e0 = part[g];
        for (int j = g * 4; j < i; j++) e0 += cnt[j];
        excl[i] = e0;
    }
    __syncthreads();
    for (int i = t; i < NPB; i += 256) {
        rp[n0 + i] = ebase + excl[i];
        cnt[i] = excl[i];
    }
    if (b == NBUCK - 1 && t == 0) rp[N_NODES] = N_EDGES;
    __syncthreads();
    for (int e = ebase + t; e < eend; e += 256) {
        int2 p = bkt[e];
        int pos = ebase + atomicAdd(&cnt[p.y - n0], 1);
        csr_src[pos] = p.x;
    }
}

// ---------------------------------------------------------------------------
// Dual GEMM, register-resident W. Block = GEMM_NT nodes, 4 waves; wave w owns
// feats [32w,32w+32). tau loop NOT unrolled (keeps wfrag resident in VGPRs),
// h fragments double-buffered (prefetch next tau before MFMAs).
// MFMA: A=W rows, B=h rows => D: col=node, row=feat (4 consecutive per lane).
// ---------------------------------------------------------------------------
template<bool ABF16>
__global__ __launch_bounds__(256) void dual_gemm_kernel(
    const void* __restrict__ hv,
    const __bf16* __restrict__ Wl, const __bf16* __restrict__ Wr,
    const float* __restrict__ bias,
    __bf16* __restrict__ out_l, __bf16* __restrict__ out_r, int M)
{
    const int wave = threadIdx.x >> 6;
    const int lane = threadIdx.x & 63;
    const int kq = lane >> 4;
    const int ln = lane & 15;
    const int node_base = blockIdx.x * GEMM_NT;
    const int f_base = wave * 32;
    const int NT16 = GEMM_NT / 16;

    bf16x8 wfrag[2][2][4];
    #pragma unroll
    for (int t = 0; t < 2; t++) {
        int wrow = f_base + t * 16 + ln;
        #pragma unroll
        for (int kc = 0; kc < 4; kc++) {
            int k0 = kc * 32 + kq * 8;
            wfrag[0][t][kc] = *(const bf16x8*)(Wl + wrow * 128 + k0);
            wfrag[1][t][kc] = *(const bf16x8*)(Wr + wrow * 128 + k0);
        }
    }
    float4 bias4[2];
    bias4[0] = *(const float4*)(bias + f_base + kq * 4);
    bias4[1] = *(const float4*)(bias + f_base + 16 + kq * 4);

    auto load_h = [&](int tau, bf16x8* hf) {
        int node = node_base + tau * 16 + ln;
        int nodec = node < M ? node : (M - 1);
        if constexpr (ABF16) {
            const __bf16* hrow = ((const __bf16*)hv) + (size_t)nodec * 128;
            #pragma unroll
            for (int kc = 0; kc < 4; kc++)
                hf[kc] = *(const bf16x8*)(hrow + kc * 32 + kq * 8);
        } else {
            const float* hrow = ((const float*)hv) + (size_t)nodec * 128;
            #pragma unroll
            for (int kc = 0; kc < 4; kc++) {
                int k0 = kc * 32 + kq * 8;
                float4 v0 = *(const float4*)(hrow + k0);
                float4 v1 = *(const float4*)(hrow + k0 + 4);
                bf16x8 a;
                a[0] = (__bf16)v0.x; a[1] = (__bf16)v0.y; a[2] = (__bf16)v0.z; a[3] = (__bf16)v0.w;
                a[4] = (__bf16)v1.x; a[5] = (__bf16)v1.y; a[6] = (__bf16)v1.z; a[7] = (__bf16)v1.w;
                hf[kc] = a;
            }
        }
    };

    bf16x8 hcur[4], hnext[4];
    load_h(0, hcur);

    #pragma unroll 1
    for (int tau = 0; tau < NT16; tau++) {
        if (tau + 1 < NT16) load_h(tau + 1, hnext);

        f32x4 accl[2] = {(f32x4)(0.f), (f32x4)(0.f)};
        f32x4 accr[2] = {(f32x4)(0.f), (f32x4)(0.f)};
        #pragma unroll
        for (int kc = 0; kc < 4; kc++) {
            #pragma unroll
            for (int t = 0; t < 2; t++) {
                accl[t] = __builtin_amdgcn_mfma_f32_16x16x32_bf16(wfrag[0][t][kc], hcur[kc], accl[t], 0, 0, 0);
                accr[t] = __builtin_amdgcn_mfma_f32_16x16x32_bf16(wfrag[1][t][kc], hcur[kc], accr[t], 0, 0, 0);
            }
        }

        int node = node_base + tau * 16 + ln;
        if (node < M) {
            size_t rowoff = (size_t)node * 128;
            #pragma unroll
            for (int t = 0; t < 2; t++) {
                int fc = f_base + t * 16 + kq * 4;
                ushort4 ol;
                ol.x = f2bf(accl[t][0]); ol.y = f2bf(accl[t][1]);
                ol.z = f2bf(accl[t][2]); ol.w = f2bf(accl[t][3]);
                *(ushort4*)(out_l + rowoff + fc) = ol;
                ushort4 orr;
                orr.x = f2bf(accr[t][0] + bias4[t].x);
                orr.y = f2bf(accr[t][1] + bias4[t].y);
                orr.z = f2bf(accr[t][2] + bias4[t].z);
                orr.w = f2bf(accr[t][3] + bias4[t].w);
                *(ushort4*)(out_r + rowoff + fc) = orr;
            }
        }

        #pragma unroll
        for (int kc = 0; kc < 4; kc++) hcur[kc] = hnext[kc];
    }
}

// ---------------------------------------------------------------------------
// CSR gather-aggregate: out[n] = (relu?)(base[n] + sum_j hl[csr_src[j]])
// All bf16 I/O, fp32 accumulate. 16 lanes per node; j-loop unrolled x4.
// ---------------------------------------------------------------------------
template<bool RELU>
__global__ __launch_bounds__(256) void gather_kernel(
    const __bf16* __restrict__ hl, const int* __restrict__ rp,
    const int* __restrict__ csr_src, const __bf16* __restrict__ base,
    __bf16* __restrict__ outp, int N)
{
    int nid = blockIdx.x * 16 + (threadIdx.x >> 4);
    if (nid >= N) return;
    int f8 = threadIdx.x & 15;
    int start = rp[nid], end = rp[nid + 1];

    bf16x8 b8 = ((const bf16x8*)base)[(size_t)nid * 16 + f8];
    float a[8];
    #pragma unroll
    for (int i = 0; i < 8; i++) a[i] = (float)b8[i];

    int j = start;
    for (; j + 3 < end; j += 4) {
        int s0 = csr_src[j];
        int s1 = csr_src[j + 1];
        int s2 = csr_src[j + 2];
        int s3 = csr_src[j + 3];
        bf16x8 u0 = ((const bf16x8*)hl)[(size_t)s0 * 16 + f8];
        bf16x8 u1 = ((const bf16x8*)hl)[(size_t)s1 * 16 + f8];
        bf16x8 u2 = ((const bf16x8*)hl)[(size_t)s2 * 16 + f8];
        bf16x8 u3 = ((const bf16x8*)hl)[(size_t)s3 * 16 + f8];
        #pragma unroll
        for (int i = 0; i < 8; i++)
            a[i] += ((float)u0[i] + (float)u1[i]) + ((float)u2[i] + (float)u3[i]);
    }
    for (; j < end; j++) {
        int s0 = csr_src[j];
        bf16x8 u0 = ((const bf16x8*)hl)[(size_t)s0 * 16 + f8];
        #pragma unroll
        for (int i = 0; i < 8; i++) a[i] += (float)u0[i];
    }
    bf16x8 o;
    #pragma unroll
    for (int i = 0; i < 8; i++) {
        float v = RELU ? fmaxf(a[i], 0.f) : a[i];
        o[i] = (__bf16)v;
    }
    ((bf16x8*)outp)[(size_t)nid * 16 + f8] = o;
}

// ---------------------------------------------------------------------------
// Pool: pooled[batch[n]] += h[n] (bf16 in, fp32 acc/out). batch sorted.
// ---------------------------------------------------------------------------
__global__ __launch_bounds__(256) void pool_kernel(
    const __bf16* __restrict__ h, const int* __restrict__ batch,
    float* __restrict__ pooled, int N)
{
    int idx = blockIdx.x * 256 + threadIdx.x;
    int f = idx & 127;
    int chunk = idx >> 7;
    int n0 = chunk * 32;
    if (n0 >= N) return;
    int n1 = n0 + 32; if (n1 > N) n1 = N;
    int curb = batch[n0];
    float acc = 0.f;
    for (int n = n0; n < n1; n++) {
        int b = batch[n];
        if (b != curb) {
            unsafeAtomicAdd(&pooled[(size_t)curb * 128 + f], acc);
            acc = 0.f; curb = b;
        }
        acc += (float)h[(size_t)n * 128 + f];
    }
    unsafeAtomicAdd(&pooled[(size_t)curb * 128 + f], acc);
}

__global__ void final_gemm_kernel(
    const float* __restrict__ pooled, const float* __restrict__ Wout,
    const float* __restrict__ bout, float* __restrict__ out)
{
    int idx = blockIdx.x * 64 + threadIdx.x;
    if (idx < NUM_GRAPHS * N_CLASSES) {
        int g = idx / N_CLASSES;
        int c = idx % N_CLASSES;
        float acc = bout[c];
        for (int k = 0; k < HIDDEN; k++)
            acc += pooled[g * HIDDEN + k] * Wout[c * HIDDEN + k];
        out[idx] = acc;
    }
}

extern "C" void kernel_launch(void* const* d_in, const int* in_sizes, int n_in,
                              void* d_out, int out_size, void* d_ws, size_t ws_size,
                              hipStream_t stream) {
    const float* x     = (const float*)d_in[0];
    const int*   ei    = (const int*)d_in[1];
    const int*   batch = (const int*)d_in[2];
    const float* W1l = (const float*)d_in[3];
    const float* b1  = (const float*)d_in[4];
    const float* W1r = (const float*)d_in[5];
    const float* W2l = (const float*)d_in[6];
    const float* b2  = (const float*)d_in[7];
    const float* W2r = (const float*)d_in[8];
    const float* W3l = (const float*)d_in[9];
    const float* b3  = (const float*)d_in[10];
    const float* W3r = (const float*)d_in[11];
    const float* Wout = (const float*)d_in[12];
    const float* bout = (const float*)d_in[13];
    float* out = (float*)d_out;

    char* ws = (char*)d_ws;
    size_t off = 0;
    __bf16* bufL  = (__bf16*)(ws + off); off += (size_t)N_NODES * 128 * sizeof(__bf16);
    __bf16* bufR  = (__bf16*)(ws + off); off += (size_t)N_NODES * 128 * sizeof(__bf16);
    __bf16* bufH  = (__bf16*)(ws + off); off += (size_t)N_NODES * 128 * sizeof(__bf16);
    float* pooled = (float*)(ws + off);  off += (size_t)NUM_GRAPHS * HIDDEN * sizeof(float);
    __bf16* wbf   = (__bf16*)(ws + off); off += 6 * (size_t)HIDDEN * D_FEAT * sizeof(__bf16);
    int* rp       = (int*)(ws + off);    off += ((size_t)N_NODES + 16) * sizeof(int);
    int* csr_src  = (int*)(ws + off);    off += (size_t)N_EDGES * sizeof(int);
    int2* bkt     = (int2*)(ws + off);   off += (size_t)N_EDGES * sizeof(int2);
    int* bh       = (int*)(ws + off);    off += (NBUCK + 8) * sizeof(int);
    int* bbase    = (int*)(ws + off);    off += (NBUCK + 8) * sizeof(int);
    int* bcur     = (int*)(ws + off);    off += (NBUCK + 8) * sizeof(int);

    const int WSZ = HIDDEN * D_FEAT;

    conv_w6_kernel<<<6 * 64, 256, 0, stream>>>(W1l, W1r, W2l, W2r, W3l, W3r, wbf);

    // Bucket-based CSR build (all-dense writes)
    hipMemsetAsync(bh, 0, NBUCK * sizeof(int), stream);
    bucket_hist_kernel<<<128, 256, 0, stream>>>(ei, bh);
    bucket_scan_kernel<<<1, 256, 0, stream>>>(bh, bbase, bcur);
    bucket_scatter_kernel<<<128, 256, 0, stream>>>(ei, bcur, bkt);
    bucket_csr_kernel<<<NBUCK, 256, 0, stream>>>(bkt, bbase, rp, csr_src);

    const int gemm_grid = (N_NODES + GEMM_NT - 1) / GEMM_NT;
    const int gath_grid = (N_NODES + 15) / 16;

    // Layer 1
    dual_gemm_kernel<false><<<gemm_grid, 256, 0, stream>>>(x, wbf + 0 * WSZ, wbf + 1 * WSZ, b1, bufL, bufR, N_NODES);
    gather_kernel<true><<<gath_grid, 256, 0, stream>>>(bufL, rp, csr_src, bufR, bufH, N_NODES);

    // Layer 2
    dual_gemm_kernel<true><<<gemm_grid, 256, 0, stream>>>(bufH, wbf + 2 * WSZ, wbf + 3 * WSZ, b2, bufL, bufR, N_NODES);
    gather_kernel<true><<<gath_grid, 256, 0, stream>>>(bufL, rp, csr_src, bufR, bufH, N_NODES);

    // Layer 3 (no relu)
    dual_gemm_kernel<true><<<gemm_grid, 256, 0, stream>>>(bufH, wbf + 4 * WSZ, wbf + 5 * WSZ, b3, bufL, bufR, N_NODES);
    gather_kernel<false><<<gath_grid, 256, 0, stream>>>(bufL, rp, csr_src, bufR, bufH, N_NODES);

    // Pool + final
    hipMemsetAsync(pooled, 0, (size_t)NUM_GRAPHS * HIDDEN * sizeof(float), stream);
    const int pool_grid = ((N_NODES + 31) / 32 * 128 + 255) / 256;
    pool_kernel<<<pool_grid, 256, 0, stream>>>(bufH, batch, pooled, N_NODES);
    final_gemm_kernel<<<10, 64, 0, stream>>>(pooled, Wout, bout, out);
}

// Round 8
// 471.876 us; speedup vs baseline: 1.4538x; 1.0587x over previous
//
#include <hip/hip_runtime.h>
#include <hip/hip_bf16.h>

#define N_NODES  100000
#define N_EDGES  1600000
#define D_FEAT   128
#define HIDDEN   128
#define N_CLASSES 10
#define NUM_GRAPHS 64

#define NBUCK 250        // dst buckets
#define NPB   400        // nodes per bucket (250*400 = 100000 exactly)
#define CHUNK 12500      // edges per block in passes A/C (128*12500 = 1.6M exactly)
#define GT    128        // nodes per GEMM tile
#define NPAD  100096     // N_NODES padded to GT multiple (782*128)

typedef __bf16 bf16x8 __attribute__((ext_vector_type(8)));
typedef float  f32x4  __attribute__((ext_vector_type(4)));

static __device__ __forceinline__ unsigned short f2bf(float f) {
    __bf16 b = (__bf16)f;
    return __builtin_bit_cast(unsigned short, b);
}

// async global->LDS, 16B per lane. LDS dest must be wave-uniform base + lane*16.
static __device__ __forceinline__ void async_copy16(void* lds, const void* g) {
    __builtin_amdgcn_global_load_lds(
        (const __attribute__((address_space(1))) void*)g,
        (__attribute__((address_space(3))) void*)lds, 16, 0, 0);
}

// ---------------------------------------------------------------------------
// Convert all 6 fp32 weight matrices to bf16 in one launch.
// ---------------------------------------------------------------------------
__global__ void conv_w6_kernel(const float* __restrict__ W0, const float* __restrict__ W1,
                               const float* __restrict__ W2, const float* __restrict__ W3,
                               const float* __restrict__ W4, const float* __restrict__ W5,
                               __bf16* __restrict__ out) {
    const float* Ws[6] = {W0, W1, W2, W3, W4, W5};
    int m = blockIdx.x >> 6;
    int i = (blockIdx.x & 63) * 256 + threadIdx.x;
    out[m * (HIDDEN * D_FEAT) + i] = (__bf16)Ws[m][i];
}

// ---------------------------------------------------------------------------
// x (fp32) -> bf16, 8 elems per thread. 12.8M elems = 6250 blocks.
// ---------------------------------------------------------------------------
__global__ __launch_bounds__(256) void xconv_kernel(const float* __restrict__ x,
                                                    __bf16* __restrict__ out) {
    int i = blockIdx.x * 256 + threadIdx.x;
    float4 v0 = ((const float4*)x)[i * 2];
    float4 v1 = ((const float4*)x)[i * 2 + 1];
    bf16x8 o;
    o[0] = (__bf16)v0.x; o[1] = (__bf16)v0.y; o[2] = (__bf16)v0.z; o[3] = (__bf16)v0.w;
    o[4] = (__bf16)v1.x; o[5] = (__bf16)v1.y; o[6] = (__bf16)v1.z; o[7] = (__bf16)v1.w;
    ((bf16x8*)out)[i] = o;
}

// ---------------------------------------------------------------------------
// Pass A: bucket histogram via LDS
// ---------------------------------------------------------------------------
__global__ __launch_bounds__(256) void bucket_hist_kernel(const int* __restrict__ ei,
                                                          int* __restrict__ bh) {
    __shared__ int h[NBUCK];
    int t = threadIdx.x;
    for (int i = t; i < NBUCK; i += 256) h[i] = 0;
    __syncthreads();
    int e0 = blockIdx.x * CHUNK;
    for (int e = e0 + t; e < e0 + CHUNK; e += 256) {
        int d = ei[N_EDGES + e];
        atomicAdd(&h[d / NPB], 1);
    }
    __syncthreads();
    for (int i = t; i < NBUCK; i += 256) atomicAdd(&bh[i], h[i]);
}

// ---------------------------------------------------------------------------
// Pass B: single-block exclusive scan of bucket counts -> bases + cursors
// ---------------------------------------------------------------------------
__global__ __launch_bounds__(256) void bucket_scan_kernel(const int* __restrict__ bh,
                                                          int* __restrict__ bbase,
                                                          int* __restrict__ bcur) {
    __shared__ int tmp[256];
    int t = threadIdx.x;
    int v = (t < NBUCK) ? bh[t] : 0;
    tmp[t] = v;
    __syncthreads();
    for (int off = 1; off < 256; off <<= 1) {
        int x = (t >= off) ? tmp[t - off] : 0;
        __syncthreads();
        tmp[t] += x;
        __syncthreads();
    }
    if (t < NBUCK) { int e = tmp[t] - v; bbase[t] = e; bcur[t] = e; }
    if (t == NBUCK - 1) bbase[NBUCK] = tmp[t];
}

// ---------------------------------------------------------------------------
// Pass C: partition edges into bucket-major int2{src,dst}.
// ---------------------------------------------------------------------------
__global__ __launch_bounds__(256) void bucket_scatter_kernel(const int* __restrict__ ei,
                                                             int* __restrict__ bcur,
                                                             int2* __restrict__ bkt) {
    __shared__ int h[NBUCK];
    __shared__ int lbase[NBUCK];
    int t = threadIdx.x;
    for (int i = t; i < NBUCK; i += 256) h[i] = 0;
    __syncthreads();
    int e0 = blockIdx.x * CHUNK;
    for (int e = e0 + t; e < e0 + CHUNK; e += 256) {
        int d = ei[N_EDGES + e];
        atomicAdd(&h[d / NPB], 1);
    }
    __syncthreads();
    for (int i = t; i < NBUCK; i += 256) {
        lbase[i] = atomicAdd(&bcur[i], h[i]);
        h[i] = 0;
    }
    __syncthreads();
    for (int e = e0 + t; e < e0 + CHUNK; e += 256) {
        int s = ei[e];
        int d = ei[N_EDGES + e];
        int bb = d / NPB;
        int pos = lbase[bb] + atomicAdd(&h[bb], 1);
        bkt[pos] = make_int2(s, d);
    }
}

// ---------------------------------------------------------------------------
// Pass D: one block per bucket -> rp + csr_src (dense writes)
// ---------------------------------------------------------------------------
__global__ __launch_bounds__(256) void bucket_csr_kernel(const int2* __restrict__ bkt,
                                                         const int* __restrict__ bbase,
                                                         int* __restrict__ rp,
                                                         int* __restrict__ csr_src) {
    const int b = blockIdx.x;
    const int n0 = b * NPB;
    const int ebase = bbase[b], eend = bbase[b + 1];
    __shared__ int cnt[NPB];
    __shared__ int part[128];
    __shared__ int excl[NPB];
    int t = threadIdx.x;
    for (int i = t; i < NPB; i += 256) cnt[i] = 0;
    __syncthreads();
    for (int e = ebase + t; e < eend; e += 256) {
        int2 p = bkt[e];
        atomicAdd(&cnt[p.y - n0], 1);
    }
    __syncthreads();
    int gs = 0;
    if (t < 100) { gs = cnt[4 * t] + cnt[4 * t + 1] + cnt[4 * t + 2] + cnt[4 * t + 3]; part[t] = gs; }
    else if (t < 128) part[t] = 0;
    __syncthreads();
    for (int off = 1; off < 128; off <<= 1) {
        int x = 0;
        if (t < 128 && t >= off) x = part[t - off];
        __syncthreads();
        if (t < 128) part[t] += x;
        __syncthreads();
    }
    if (t < 100) part[t] -= gs;
    __syncthreads();
    for (int i = t; i < NPB; i += 256) {
        int g = i >> 2;
        int e0 = part[g];
        for (int j = g * 4; j < i; j++) e0 += cnt[j];
        excl[i] = e0;
    }
    __syncthreads();
    for (int i = t; i < NPB; i += 256) {
        rp[n0 + i] = ebase + excl[i];
        cnt[i] = excl[i];
    }
    if (b == NBUCK - 1 && t == 0) rp[N_NODES] = N_EDGES;
    __syncthreads();
    for (int e = ebase + t; e < eend; e += 256) {
        int2 p = bkt[e];
        int pos = ebase + atomicAdd(&cnt[p.y - n0], 1);
        csr_src[pos] = p.x;
    }
}

// ---------------------------------------------------------------------------
// Dual GEMM, LDS-staged h (canonical §5 pattern):
//   out_l = h@Wl.T (bf16), out_r = h@Wr.T + b (bf16)
// One block = one 128-node tile. Fill 32KB h-tile via global_load_lds (16B,
// fully coalesced, XOR-swizzled columns so ds_read is ~conflict-free), then
// 8 taus of (4 ds_read_b128 + 16 MFMA + 4 stores) per wave. W register-
// resident. h must be padded to NPAD rows. MFMA: A=W, B=h => D col=node.
// ---------------------------------------------------------------------------
__global__ __launch_bounds__(256) void dual_gemm_kernel(
    const __bf16* __restrict__ h,
    const __bf16* __restrict__ Wl, const __bf16* __restrict__ Wr,
    const float* __restrict__ bias,
    __bf16* __restrict__ out_l, __bf16* __restrict__ out_r, int M)
{
    __shared__ __bf16 tile_lds[GT * 128];   // 32 KB

    const int tid  = threadIdx.x;
    const int wave = tid >> 6;
    const int lane = tid & 63;
    const int kq = lane >> 4;
    const int ln = lane & 15;
    const int node_base = blockIdx.x * GT;
    const int f_base = wave * 32;

    // ---- async fill: 2048 16B units; unit u: row=u>>4, col16 = (u&15) ^ (row&15)
    {
        const __bf16* hsrc = h + (size_t)node_base * 128;
        #pragma unroll
        for (int i = 0; i < 8; i++) {
            int u = i * 256 + tid;
            int row = u >> 4;
            int sc = (u & 15) ^ (row & 15);
            async_copy16(&tile_lds[u * 8], hsrc + row * 128 + sc * 8);
        }
    }

    // ---- W fragments resident (loads overlap the fill; barrier drains both)
    bf16x8 wfrag[2][2][4];
    #pragma unroll
    for (int t = 0; t < 2; t++) {
        int wrow = f_base + t * 16 + ln;
        #pragma unroll
        for (int kc = 0; kc < 4; kc++) {
            int k0 = kc * 32 + kq * 8;
            wfrag[0][t][kc] = *(const bf16x8*)(Wl + wrow * 128 + k0);
            wfrag[1][t][kc] = *(const bf16x8*)(Wr + wrow * 128 + k0);
        }
    }
    float4 bias4[2];
    bias4[0] = *(const float4*)(bias + f_base + kq * 4);
    bias4[1] = *(const float4*)(bias + f_base + 16 + kq * 4);

    __syncthreads();   // drains global_load_lds (vmcnt) + all waves arrived

    #pragma unroll 2
    for (int tau = 0; tau < GT / 16; tau++) {
        int r = tau * 16 + ln;
        // fragment: logical col16 = 4*kc+kq, physical col = (4kc+kq) ^ (r&15)=(..)^ln
        bf16x8 hfrag[4];
        #pragma unroll
        for (int kc = 0; kc < 4; kc++) {
            int c = (4 * kc + kq) ^ ln;
            hfrag[kc] = *(const bf16x8*)&tile_lds[r * 128 + c * 8];
        }

        f32x4 accl[2] = {(f32x4)(0.f), (f32x4)(0.f)};
        f32x4 accr[2] = {(f32x4)(0.f), (f32x4)(0.f)};
        #pragma unroll
        for (int kc = 0; kc < 4; kc++) {
            #pragma unroll
            for (int t = 0; t < 2; t++) {
                accl[t] = __builtin_amdgcn_mfma_f32_16x16x32_bf16(wfrag[0][t][kc], hfrag[kc], accl[t], 0, 0, 0);
                accr[t] = __builtin_amdgcn_mfma_f32_16x16x32_bf16(wfrag[1][t][kc], hfrag[kc], accr[t], 0, 0, 0);
            }
        }

        int node = node_base + tau * 16 + ln;
        if (node < M) {
            size_t rowoff = (size_t)node * 128;
            #pragma unroll
            for (int t = 0; t < 2; t++) {
                int fc = f_base + t * 16 + kq * 4;
                ushort4 ol;
                ol.x = f2bf(accl[t][0]); ol.y = f2bf(accl[t][1]);
                ol.z = f2bf(accl[t][2]); ol.w = f2bf(accl[t][3]);
                *(ushort4*)(out_l + rowoff + fc) = ol;
                ushort4 orr;
                orr.x = f2bf(accr[t][0] + bias4[t].x);
                orr.y = f2bf(accr[t][1] + bias4[t].y);
                orr.z = f2bf(accr[t][2] + bias4[t].z);
                orr.w = f2bf(accr[t][3] + bias4[t].w);
                *(ushort4*)(out_r + rowoff + fc) = orr;
            }
        }
    }
}

// ---------------------------------------------------------------------------
// CSR gather-aggregate: out[n] = (relu?)(base[n] + sum_j hl[csr_src[j]])
// All bf16 I/O, fp32 accumulate. 16 lanes per node; j-loop unrolled x4.
// ---------------------------------------------------------------------------
template<bool RELU>
__global__ __launch_bounds__(256) void gather_kernel(
    const __bf16* __restrict__ hl, const int* __restrict__ rp,
    const int* __restrict__ csr_src, const __bf16* __restrict__ base,
    __bf16* __restrict__ outp, int N)
{
    int nid = blockIdx.x * 16 + (threadIdx.x >> 4);
    if (nid >= N) return;
    int f8 = threadIdx.x & 15;
    int start = rp[nid], end = rp[nid + 1];

    bf16x8 b8 = ((const bf16x8*)base)[(size_t)nid * 16 + f8];
    float a[8];
    #pragma unroll
    for (int i = 0; i < 8; i++) a[i] = (float)b8[i];

    int j = start;
    for (; j + 3 < end; j += 4) {
        int s0 = csr_src[j];
        int s1 = csr_src[j + 1];
        int s2 = csr_src[j + 2];
        int s3 = csr_src[j + 3];
        bf16x8 u0 = ((const bf16x8*)hl)[(size_t)s0 * 16 + f8];
        bf16x8 u1 = ((const bf16x8*)hl)[(size_t)s1 * 16 + f8];
        bf16x8 u2 = ((const bf16x8*)hl)[(size_t)s2 * 16 + f8];
        bf16x8 u3 = ((const bf16x8*)hl)[(size_t)s3 * 16 + f8];
        #pragma unroll
        for (int i = 0; i < 8; i++)
            a[i] += ((float)u0[i] + (float)u1[i]) + ((float)u2[i] + (float)u3[i]);
    }
    for (; j < end; j++) {
        int s0 = csr_src[j];
        bf16x8 u0 = ((const bf16x8*)hl)[(size_t)s0 * 16 + f8];
        #pragma unroll
        for (int i = 0; i < 8; i++) a[i] += (float)u0[i];
    }
    bf16x8 o;
    #pragma unroll
    for (int i = 0; i < 8; i++) {
        float v = RELU ? fmaxf(a[i], 0.f) : a[i];
        o[i] = (__bf16)v;
    }
    ((bf16x8*)outp)[(size_t)nid * 16 + f8] = o;
}

// ---------------------------------------------------------------------------
// Pool: pooled[batch[n]] += h[n] (bf16 in, fp32 acc/out). batch sorted.
// ---------------------------------------------------------------------------
__global__ __launch_bounds__(256) void pool_kernel(
    const __bf16* __restrict__ h, const int* __restrict__ batch,
    float* __restrict__ pooled, int N)
{
    int idx = blockIdx.x * 256 + threadIdx.x;
    int f = idx & 127;
    int chunk = idx >> 7;
    int n0 = chunk * 32;
    if (n0 >= N) return;
    int n1 = n0 + 32; if (n1 > N) n1 = N;
    int curb = batch[n0];
    float acc = 0.f;
    for (int n = n0; n < n1; n++) {
        int b = batch[n];
        if (b != curb) {
            unsafeAtomicAdd(&pooled[(size_t)curb * 128 + f], acc);
            acc = 0.f; curb = b;
        }
        acc += (float)h[(size_t)n * 128 + f];
    }
    unsafeAtomicAdd(&pooled[(size_t)curb * 128 + f], acc);
}

__global__ void final_gemm_kernel(
    const float* __restrict__ pooled, const float* __restrict__ Wout,
    const float* __restrict__ bout, float* __restrict__ out)
{
    int idx = blockIdx.x * 64 + threadIdx.x;
    if (idx < NUM_GRAPHS * N_CLASSES) {
        int g = idx / N_CLASSES;
        int c = idx % N_CLASSES;
        float acc = bout[c];
        for (int k = 0; k < HIDDEN; k++)
            acc += pooled[g * HIDDEN + k] * Wout[c * HIDDEN + k];
        out[idx] = acc;
    }
}

extern "C" void kernel_launch(void* const* d_in, const int* in_sizes, int n_in,
                              void* d_out, int out_size, void* d_ws, size_t ws_size,
                              hipStream_t stream) {
    const float* x     = (const float*)d_in[0];
    const int*   ei    = (const int*)d_in[1];
    const int*   batch = (const int*)d_in[2];
    const float* W1l = (const float*)d_in[3];
    const float* b1  = (const float*)d_in[4];
    const float* W1r = (const float*)d_in[5];
    const float* W2l = (const float*)d_in[6];
    const float* b2  = (const float*)d_in[7];
    const float* W2r = (const float*)d_in[8];
    const float* W3l = (const float*)d_in[9];
    const float* b3  = (const float*)d_in[10];
    const float* W3r = (const float*)d_in[11];
    const float* Wout = (const float*)d_in[12];
    const float* bout = (const float*)d_in[13];
    float* out = (float*)d_out;

    char* ws = (char*)d_ws;
    size_t off = 0;
    __bf16* bufL  = (__bf16*)(ws + off); off += (size_t)N_NODES * 128 * sizeof(__bf16);
    __bf16* bufR  = (__bf16*)(ws + off); off += (size_t)N_NODES * 128 * sizeof(__bf16);
    __bf16* bufH  = (__bf16*)(ws + off); off += (size_t)NPAD * 128 * sizeof(__bf16); // padded (GEMM input)
    float* pooled = (float*)(ws + off);  off += (size_t)NUM_GRAPHS * HIDDEN * sizeof(float);
    __bf16* wbf   = (__bf16*)(ws + off); off += 6 * (size_t)HIDDEN * D_FEAT * sizeof(__bf16);
    int* rp       = (int*)(ws + off);    off += ((size_t)N_NODES + 16) * sizeof(int);
    int* csr_src  = (int*)(ws + off);    off += (size_t)N_EDGES * sizeof(int);
    int2* bkt     = (int2*)(ws + off);   off += (size_t)N_EDGES * sizeof(int2);
    int* bh       = (int*)(ws + off);    off += (NBUCK + 8) * sizeof(int);
    int* bbase    = (int*)(ws + off);    off += (NBUCK + 8) * sizeof(int);
    int* bcur     = (int*)(ws + off);    off += (NBUCK + 8) * sizeof(int);

    const int WSZ = HIDDEN * D_FEAT;

    conv_w6_kernel<<<6 * 64, 256, 0, stream>>>(W1l, W1r, W2l, W2r, W3l, W3r, wbf);
    xconv_kernel<<<N_NODES * 128 / (256 * 8), 256, 0, stream>>>(x, bufH);

    // Bucket-based CSR build (all-dense writes)
    hipMemsetAsync(bh, 0, NBUCK * sizeof(int), stream);
    bucket_hist_kernel<<<128, 256, 0, stream>>>(ei, bh);
    bucket_scan_kernel<<<1, 256, 0, stream>>>(bh, bbase, bcur);
    bucket_scatter_kernel<<<128, 256, 0, stream>>>(ei, bcur, bkt);
    bucket_csr_kernel<<<NBUCK, 256, 0, stream>>>(bkt, bbase, rp, csr_src);

    const int gemm_grid = NPAD / GT;   // 782
    const int gath_grid = (N_NODES + 15) / 16;

    // Layer 1 (input = bf16-converted x in bufH; gather overwrites bufH after)
    dual_gemm_kernel<<<gemm_grid, 256, 0, stream>>>(bufH, wbf + 0 * WSZ, wbf + 1 * WSZ, b1, bufL, bufR, N_NODES);
    gather_kernel<true><<<gath_grid, 256, 0, stream>>>(bufL, rp, csr_src, bufR, bufH, N_NODES);

    // Layer 2
    dual_gemm_kernel<<<gemm_grid, 256, 0, stream>>>(bufH, wbf + 2 * WSZ, wbf + 3 * WSZ, b2, bufL, bufR, N_NODES);
    gather_kernel<true><<<gath_grid, 256, 0, stream>>>(bufL, rp, csr_src, bufR, bufH, N_NODES);

    // Layer 3 (no relu)
    dual_gemm_kernel<<<gemm_grid, 256, 0, stream>>>(bufH, wbf + 4 * WSZ, wbf + 5 * WSZ, b3, bufL, bufR, N_NODES);
    gather_kernel<false><<<gath_grid, 256, 0, stream>>>(bufL, rp, csr_src, bufR, bufH, N_NODES);

    // Pool + final
    hipMemsetAsync(pooled, 0, (size_t)NUM_GRAPHS * HIDDEN * sizeof(float), stream);
    const int pool_grid = ((N_NODES + 31) / 32 * 128 + 255) / 256;
    pool_kernel<<<pool_grid, 256, 0, stream>>>(bufH, batch, pooled, N_NODES);
    final_gemm_kernel<<<10, 64, 0, stream>>>(pooled, Wout, bout, out);
}